// Round 20
// baseline (190.894 us; speedup 1.0000x reference)
//
#include <hip/hip_runtime.h>
#include <hip/hip_fp16.h>

#define NN 100000
#define NE 1600000
#define NG 512
#define NC 16
#define NBUK 391  // coarse buckets = cdiv(NN,256), bucket = dst>>8
#define EPB 8192  // edges per phase-1 block
#define NB1 196   // cdiv(NE, EPB)

static inline int cdiv(long long a, int b) { return (int)((a + b - 1) / b); }

typedef __attribute__((ext_vector_type(2))) float floatx2;
typedef _Float16 half8_t __attribute__((ext_vector_type(8)));
typedef float f32x4_t __attribute__((ext_vector_type(4)));

__device__ __forceinline__ unsigned int pack_f16(float x, float y) {
  __half2 h = __floats2half2_rn(x, y);
  return *reinterpret_cast<unsigned int*>(&h);
}
__device__ __forceinline__ float2 unpack_f16(unsigned int u) {
  __half2 h = *reinterpret_cast<__half2*>(&u);
  return __half22float2(h);
}
// decode 4 fp8 (e4m3) from one uint into acc[0..3]
__device__ __forceinline__ void accf8(float* acc, unsigned int u) {
  floatx2 lo = __builtin_amdgcn_cvt_pk_f32_fp8(u, false);
  floatx2 hi = __builtin_amdgcn_cvt_pk_f32_fp8(u, true);
  acc[0] += lo.x; acc[1] += lo.y; acc[2] += hi.x; acc[3] += hi.y;
}
__device__ __forceinline__ unsigned int pack4_f8(float a, float b, float c, float d) {
  unsigned int u = 0;
  u = __builtin_amdgcn_cvt_pk_fp8_f32(a, b, u, false);
  u = __builtin_amdgcn_cvt_pk_fp8_f32(c, d, u, true);
  return u;
}
__device__ __forceinline__ half8_t as_h8(uint4 u) {
  half8_t h;
  __builtin_memcpy(&h, &u, 16);
  return h;
}

// prep: zero gsum (blocks 0..255) + build fp16 B-fragment-swizzled W3 (blocks 256..259)
__global__ void k_prep(const float* __restrict__ W3, float* __restrict__ gsum,
                       unsigned int* __restrict__ w3s) {
  int b = blockIdx.x, t = threadIdx.x;
  if (b < 256) {
    gsum[b * 256 + t] = 0.f;
    return;
  }
  int idx = (b - 256) * 256 + t;  // [0,1024)
  int c = idx >> 7, kb = (idx >> 6) & 1, l = idx & 63;
  int n = l & 15, kg = l >> 4;
#pragma unroll
  for (int j = 0; j < 4; ++j) {
    int k0 = kb * 32 + kg * 8 + 2 * j;
    w3s[idx * 4 + j] = pack_f16(W3[k0 * 128 + c * 16 + n], W3[(k0 + 1) * 128 + c * 16 + n]);
  }
}

// p1a: per-block coarse histogram (dst>>8) -> bcnt[bucket*NB1 + blk]  (LDS atomics only)
__global__ void k_p1a(const int* __restrict__ dst, int* __restrict__ bcnt) {
  __shared__ int sh[NBUK];
  int t = threadIdx.x, blk = blockIdx.x;
  for (int u = t; u < NBUK; u += 256) sh[u] = 0;
  __syncthreads();
  int e0 = blk * EPB;
#pragma unroll
  for (int k = 0; k < EPB / 256; ++k) {
    int e = e0 + k * 256 + t;
    if (e < NE) atomicAdd(&sh[dst[e] >> 8], 1);
  }
  __syncthreads();
  for (int u = t; u < NBUK; u += 256) bcnt[u * NB1 + blk] = sh[u];
}

// p1b: scatter edges into coarse-bucket partitions; packed = (dst&255)<<24 | src
__global__ void k_p1b(const int* __restrict__ src, const int* __restrict__ dst,
                      const int* __restrict__ bpos, unsigned int* __restrict__ packed) {
  __shared__ int sbase[NBUK];
  int t = threadIdx.x, blk = blockIdx.x;
  for (int u = t; u < NBUK; u += 256) sbase[u] = bpos[u * NB1 + blk];
  __syncthreads();
  int e0 = blk * EPB;
#pragma unroll
  for (int k = 0; k < EPB / 256; ++k) {
    int e = e0 + k * 256 + t;
    if (e < NE) {
      int d = dst[e];
      int pos = atomicAdd(&sbase[d >> 8], 1);  // LDS returning atomic
      packed[pos] = ((unsigned int)(d & 255) << 24) | (unsigned int)src[e];
    }
  }
}

// p2: per-bucket fine counting sort by dst-low8; emits count/offs/dinv + src-only csr
// + FUSED dense1: t1f8 = fp8((x@W1)*di)
__global__ void k_p2(const unsigned int* __restrict__ packed, const int* __restrict__ bpos,
                     const float* __restrict__ x, const float* __restrict__ W1,
                     int* __restrict__ count, int* __restrict__ offs,
                     float* __restrict__ dinv, int* __restrict__ csr,
                     unsigned int* __restrict__ t1f8) {
  __shared__ int sh[256], sc[256], cur[256];
  __shared__ float sW1[13 * 16];
  int t = threadIdx.x, u = blockIdx.x;
  if (t < 13 * 16) sW1[t] = W1[t];
  int s0 = bpos[u * NB1];
  int s1 = (u + 1 < NBUK) ? bpos[(u + 1) * NB1] : NE;
  sh[t] = 0;
  __syncthreads();
  for (int e = s0 + t; e < s1; e += 256) atomicAdd(&sh[packed[e] >> 24], 1);
  __syncthreads();
  sc[t] = sh[t];
  __syncthreads();
  for (int d = 1; d < 256; d <<= 1) {
    int a = (t >= d) ? sc[t - d] : 0;
    __syncthreads();
    sc[t] += a;
    __syncthreads();
  }
  int excl = sc[t] - sh[t];
  int node = u * 256 + t;
  if (node < NN) {
    count[node] = sh[t];
    offs[node] = s0 + excl;
    float di = rsqrtf((float)(sh[t] + 1));  // +1 self loop
    dinv[node] = di;
    // fused dense1: 16 outputs, fp8-packed
    float a[16];
#pragma unroll
    for (int o = 0; o < 16; ++o) a[o] = 0.f;
#pragma unroll
    for (int k = 0; k < 13; ++k) {
      float av = x[(size_t)node * 13 + k];
#pragma unroll
      for (int o = 0; o < 16; ++o) a[o] += av * sW1[k * 16 + o];
    }
    uint4 ov;
    ov.x = pack4_f8(a[0] * di, a[1] * di, a[2] * di, a[3] * di);
    ov.y = pack4_f8(a[4] * di, a[5] * di, a[6] * di, a[7] * di);
    ov.z = pack4_f8(a[8] * di, a[9] * di, a[10] * di, a[11] * di);
    ov.w = pack4_f8(a[12] * di, a[13] * di, a[14] * di, a[15] * di);
    ((uint4*)t1f8)[node] = ov;
  }
  cur[t] = s0 + excl;
  __syncthreads();
  for (int e = s0 + t; e < s1; e += 256) {
    unsigned int p = packed[e];
    int pos = atomicAdd(&cur[p >> 24], 1);  // LDS returning atomic
    csr[pos] = (int)(p & 0x00FFFFFFu);
  }
}

// graph boundaries from sorted batch
__global__ void k_bounds(const int* __restrict__ batch, int* __restrict__ gstart) {
  int i = blockIdx.x * blockDim.x + threadIdx.x;
  if (i > NN) return;
  int b = (i < NN) ? batch[i] : NG;
  int bp = (i > 0) ? batch[i - 1] : -1;
  for (int g = bp + 1; g <= b; ++g) gstart[g] = i;
}

// exclusive scan, 256/block; bsum gets block totals
__global__ void k_scan1(const int* __restrict__ in, int* __restrict__ out,
                        int* __restrict__ bsum, int n) {
  __shared__ int s[256];
  int t = threadIdx.x, i = blockIdx.x * 256 + t;
  int v = (i < n) ? in[i] : 0;
  s[t] = v;
  __syncthreads();
  for (int d = 1; d < 256; d <<= 1) {
    int a = (t >= d) ? s[t - d] : 0;
    __syncthreads();
    s[t] += a;
    __syncthreads();
  }
  if (i < n) out[i] = s[t] - v;  // exclusive
  if (t == 255) bsum[blockIdx.x] = s[255];
}

// single-block exclusive scan over <=512 values
__global__ void k_scan2(const int* __restrict__ in, int* __restrict__ out, int nb) {
  __shared__ int s[512];
  int t = threadIdx.x;
  int v = (t < nb) ? in[t] : 0;
  s[t] = v;
  __syncthreads();
  for (int d = 1; d < 512; d <<= 1) {
    int a = (t >= d) ? s[t - d] : 0;
    __syncthreads();
    s[t] += a;
    __syncthreads();
  }
  if (t < nb) out[t] = s[t] - v;
}

__global__ void k_scan3b(int* __restrict__ a, const int* __restrict__ bpref, int n) {
  int i = blockIdx.x * blockDim.x + threadIdx.x;
  if (i < n) a[i] += bpref[i >> 8];
}

// fp8 gather-reduce for F=16 rows (16B): 1 lane/node, uint4 per edge, unroll 8.
// BR: bias+relu epilogue (then prescale *di for next agg). OUTF8: fp8 out else fp16.
template <bool BR, bool OUTF8>
__global__ void k_agg16f8(const unsigned int* __restrict__ h, const int* __restrict__ csr,
                          const int* __restrict__ offs, const int* __restrict__ count,
                          const float* __restrict__ dinv, const float* __restrict__ bias,
                          unsigned int* __restrict__ out) {
  int wave = threadIdx.x >> 6, lane = threadIdx.x & 63;
  int i = (blockIdx.x * 4 + wave) * 64 + lane;
  if (i >= NN) return;
  int off = offs[i], cnt = count[i];
  float di = dinv[i];
  float acc[16];
#pragma unroll
  for (int t = 0; t < 16; ++t) acc[t] = 0.f;
  int j = 0;
#define DEC16(r)                                                            \
  {                                                                         \
    accf8(acc + 0, r.x);                                                    \
    accf8(acc + 4, r.y);                                                    \
    accf8(acc + 8, r.z);                                                    \
    accf8(acc + 12, r.w);                                                   \
  }
  for (; j + 7 < cnt; j += 8) {
    int s0 = csr[off + j], s1 = csr[off + j + 1];
    int s2 = csr[off + j + 2], s3 = csr[off + j + 3];
    int s4 = csr[off + j + 4], s5 = csr[off + j + 5];
    int s6 = csr[off + j + 6], s7 = csr[off + j + 7];
    uint4 r0 = ((const uint4*)h)[s0];
    uint4 r1 = ((const uint4*)h)[s1];
    uint4 r2 = ((const uint4*)h)[s2];
    uint4 r3 = ((const uint4*)h)[s3];
    uint4 r4 = ((const uint4*)h)[s4];
    uint4 r5 = ((const uint4*)h)[s5];
    uint4 r6 = ((const uint4*)h)[s6];
    uint4 r7 = ((const uint4*)h)[s7];
    DEC16(r0) DEC16(r1) DEC16(r2) DEC16(r3)
    DEC16(r4) DEC16(r5) DEC16(r6) DEC16(r7)
  }
  for (; j + 3 < cnt; j += 4) {
    int s0 = csr[off + j], s1 = csr[off + j + 1];
    int s2 = csr[off + j + 2], s3 = csr[off + j + 3];
    uint4 r0 = ((const uint4*)h)[s0];
    uint4 r1 = ((const uint4*)h)[s1];
    uint4 r2 = ((const uint4*)h)[s2];
    uint4 r3 = ((const uint4*)h)[s3];
    DEC16(r0) DEC16(r1) DEC16(r2) DEC16(r3)
  }
  for (; j < cnt; ++j) {
    uint4 r0 = ((const uint4*)h)[csr[off + j]];
    DEC16(r0)
  }
  uint4 rs = ((const uint4*)h)[i];  // self loop (prescaled)
  DEC16(rs)
#undef DEC16
  float v[16];
#pragma unroll
  for (int t = 0; t < 16; ++t) {
    v[t] = acc[t] * di;
    if (BR) v[t] = fmaxf(v[t] + bias[t], 0.f) * di;  // relu+bias then prescale
  }
  if (OUTF8) {
    uint4 o;
    o.x = pack4_f8(v[0], v[1], v[2], v[3]);
    o.y = pack4_f8(v[4], v[5], v[6], v[7]);
    o.z = pack4_f8(v[8], v[9], v[10], v[11]);
    o.w = pack4_f8(v[12], v[13], v[14], v[15]);
    ((uint4*)out)[i] = o;
  } else {
    uint4 o0, o1;
    o0.x = pack_f16(v[0], v[1]);
    o0.y = pack_f16(v[2], v[3]);
    o0.z = pack_f16(v[4], v[5]);
    o0.w = pack_f16(v[6], v[7]);
    o1.x = pack_f16(v[8], v[9]);
    o1.y = pack_f16(v[10], v[11]);
    o1.z = pack_f16(v[12], v[13]);
    o1.w = pack_f16(v[14], v[15]);
    uint4* dst = (uint4*)(out + (size_t)i * 8);
    dst[0] = o0;
    dst[1] = o1;
  }
}

// fp8 gather-reduce F=64 (64B rows): 4 lanes/node, uint4 (16 fp8) per lane, unroll 8.
// Output t3h in fp16 (k-contiguous rows for the MFMA A-fragment).
__global__ void k_agg_b64f8(const unsigned int* __restrict__ h, const int* __restrict__ csr,
                            const int* __restrict__ offs, const int* __restrict__ count,
                            const float* __restrict__ dinv, unsigned int* __restrict__ out) {
  int wave = threadIdx.x >> 6, lane = threadIdx.x & 63;
  int i = (blockIdx.x * 4 + wave) * 16 + (lane >> 2);
  int q = lane & 3;  // uint4 index within 16-uint fp8 row
  if (i >= NN) return;
  int off = offs[i], cnt = count[i];
  float di = dinv[i];
  float acc[16];
#pragma unroll
  for (int t = 0; t < 16; ++t) acc[t] = 0.f;
  int j = 0;
#define DEC16(r)                                                            \
  {                                                                         \
    accf8(acc + 0, r.x);                                                    \
    accf8(acc + 4, r.y);                                                    \
    accf8(acc + 8, r.z);                                                    \
    accf8(acc + 12, r.w);                                                   \
  }
  for (; j + 7 < cnt; j += 8) {
    int s0 = csr[off + j], s1 = csr[off + j + 1];
    int s2 = csr[off + j + 2], s3 = csr[off + j + 3];
    int s4 = csr[off + j + 4], s5 = csr[off + j + 5];
    int s6 = csr[off + j + 6], s7 = csr[off + j + 7];
    uint4 r0 = ((const uint4*)(h + (size_t)s0 * 16))[q];
    uint4 r1 = ((const uint4*)(h + (size_t)s1 * 16))[q];
    uint4 r2 = ((const uint4*)(h + (size_t)s2 * 16))[q];
    uint4 r3 = ((const uint4*)(h + (size_t)s3 * 16))[q];
    uint4 r4 = ((const uint4*)(h + (size_t)s4 * 16))[q];
    uint4 r5 = ((const uint4*)(h + (size_t)s5 * 16))[q];
    uint4 r6 = ((const uint4*)(h + (size_t)s6 * 16))[q];
    uint4 r7 = ((const uint4*)(h + (size_t)s7 * 16))[q];
    DEC16(r0) DEC16(r1) DEC16(r2) DEC16(r3)
    DEC16(r4) DEC16(r5) DEC16(r6) DEC16(r7)
  }
  for (; j + 3 < cnt; j += 4) {
    int s0 = csr[off + j], s1 = csr[off + j + 1];
    int s2 = csr[off + j + 2], s3 = csr[off + j + 3];
    uint4 r0 = ((const uint4*)(h + (size_t)s0 * 16))[q];
    uint4 r1 = ((const uint4*)(h + (size_t)s1 * 16))[q];
    uint4 r2 = ((const uint4*)(h + (size_t)s2 * 16))[q];
    uint4 r3 = ((const uint4*)(h + (size_t)s3 * 16))[q];
    DEC16(r0) DEC16(r1) DEC16(r2) DEC16(r3)
  }
  for (; j < cnt; ++j) {
    uint4 r0 = ((const uint4*)(h + (size_t)csr[off + j] * 16))[q];
    DEC16(r0)
  }
  uint4 rs = ((const uint4*)(h + (size_t)i * 16))[q];  // self loop (prescaled)
  DEC16(rs)
#undef DEC16
  uint4 o0, o1;
  o0.x = pack_f16(acc[0] * di, acc[1] * di);
  o0.y = pack_f16(acc[2] * di, acc[3] * di);
  o0.z = pack_f16(acc[4] * di, acc[5] * di);
  o0.w = pack_f16(acc[6] * di, acc[7] * di);
  o1.x = pack_f16(acc[8] * di, acc[9] * di);
  o1.y = pack_f16(acc[10] * di, acc[11] * di);
  o1.z = pack_f16(acc[12] * di, acc[13] * di);
  o1.w = pack_f16(acc[14] * di, acc[15] * di);
  uint4* dst = (uint4*)(out + (size_t)i * 32 + q * 8);
  dst[0] = o0;
  dst[1] = o1;
}

// dense2: h2f8 = fp8(relu(t2@W2+b2)*di); fp16-packed input rows; 4 outputs/thread
__global__ void k_dense2_f8(const unsigned int* __restrict__ a, const float* __restrict__ W,
                            const float* __restrict__ b, const float* __restrict__ dinv,
                            unsigned int* __restrict__ out, int n) {
  __shared__ float sW[16 * 64];
  __shared__ float sb[64];
  for (int t = threadIdx.x; t < 16 * 64; t += blockDim.x) sW[t] = W[t];
  for (int t = threadIdx.x; t < 64; t += blockDim.x) sb[t] = b[t];
  __syncthreads();
  int idx = blockIdx.x * blockDim.x + threadIdx.x;
  int i = idx >> 4, g4 = idx & 15;  // group of 4 output features
  if (i >= n) return;
  float av[16];
#pragma unroll
  for (int u = 0; u < 8; ++u) {
    float2 p = unpack_f16(a[(size_t)i * 8 + u]);
    av[2 * u] = p.x;
    av[2 * u + 1] = p.y;
  }
  float acc[4];
#pragma unroll
  for (int ko = 0; ko < 4; ++ko) acc[ko] = sb[4 * g4 + ko];
#pragma unroll
  for (int k = 0; k < 16; ++k) {
#pragma unroll
    for (int ko = 0; ko < 4; ++ko) acc[ko] += av[k] * sW[k * 64 + 4 * g4 + ko];
  }
  float di = dinv[i];
#pragma unroll
  for (int ko = 0; ko < 4; ++ko) acc[ko] = fmaxf(acc[ko], 0.f) * di;
  out[(size_t)i * 16 + g4] = pack4_f8(acc[0], acc[1], acc[2], acc[3]);
}

// MFMA dense3(64->128)+relu+segmented mean-pool.
__global__ __launch_bounds__(256) void k_d3pool_mfma(
    const unsigned int* __restrict__ t3h, const unsigned int* __restrict__ w3s,
    const float* __restrict__ b3, const int* __restrict__ batch,
    float* __restrict__ gsum) {
  int wu = blockIdx.x * 4 + (threadIdx.x >> 6);
  int lane = threadIdx.x & 63;
  int n0 = wu * 16;
  if (n0 >= NN) return;
  uint4 bf[8][2];
#pragma unroll
  for (int c = 0; c < 8; ++c)
#pragma unroll
    for (int kb = 0; kb < 2; ++kb)
      bf[c][kb] = ((const uint4*)w3s)[(c * 2 + kb) * 64 + lane];
  const uint4* arow = (const uint4*)(t3h + (size_t)(n0 + (lane & 15)) * 32);
  uint4 a0 = arow[lane >> 4];
  uint4 a1 = arow[4 + (lane >> 4)];
  f32x4_t acc[8];
#pragma unroll
  for (int c = 0; c < 8; ++c) {
    f32x4_t z = {0.f, 0.f, 0.f, 0.f};
    z = __builtin_amdgcn_mfma_f32_16x16x32_f16(as_h8(a0), as_h8(bf[c][0]), z, 0, 0, 0);
    z = __builtin_amdgcn_mfma_f32_16x16x32_f16(as_h8(a1), as_h8(bf[c][1]), z, 0, 0, 0);
    acc[c] = z;
  }
  float bias[8];
#pragma unroll
  for (int c = 0; c < 8; ++c) bias[c] = b3[c * 16 + (lane & 15)];
  int gf = batch[n0], gl = batch[n0 + 15];
  if (gf == gl) {
#pragma unroll
    for (int c = 0; c < 8; ++c) {
      float s = fmaxf(acc[c][0] + bias[c], 0.f) + fmaxf(acc[c][1] + bias[c], 0.f) +
                fmaxf(acc[c][2] + bias[c], 0.f) + fmaxf(acc[c][3] + bias[c], 0.f);
      s += __shfl_xor(s, 16);
      s += __shfl_xor(s, 32);
      if (lane < 16) atomicAdd(&gsum[gf * 128 + c * 16 + lane], s);
    }
  } else {
#pragma unroll
    for (int r = 0; r < 4; ++r) {
      int g = batch[n0 + (lane >> 4) * 4 + r];
#pragma unroll
      for (int c = 0; c < 8; ++c)
        atomicAdd(&gsum[g * 128 + c * 16 + (lane & 15)],
                  fmaxf(acc[c][r] + bias[c], 0.f));
    }
  }
}

// one wave per graph: logits = (gsum/cnt) @ Wl + bl; log_softmax over 16 classes
__global__ void k_head(const float* __restrict__ gsum, const int* __restrict__ gstart,
                       const float* __restrict__ Wl, const float* __restrict__ bl,
                       float* __restrict__ out) {
  int wave = threadIdx.x >> 6, lane = threadIdx.x & 63;
  int g = blockIdx.x * 4 + wave;
  if (g >= NG) return;
  int c = lane & 15, part = lane >> 4;
  float acc = 0.f;
#pragma unroll
  for (int kk = 0; kk < 32; ++kk) {
    int k = part * 32 + kk;
    acc += gsum[g * 128 + k] * Wl[k * NC + c];
  }
  acc += __shfl_xor(acc, 16);
  acc += __shfl_xor(acc, 32);
  int cnt = gstart[g + 1] - gstart[g];
  float inv = 1.0f / (float)max(cnt, 1);
  float logit = acc * inv + bl[c];
  float m = logit;
#pragma unroll
  for (int d = 1; d < 16; d <<= 1) m = fmaxf(m, __shfl_xor(m, d));
  float ex = expf(logit - m), s = ex;
#pragma unroll
  for (int d = 1; d < 16; d <<= 1) s += __shfl_xor(s, d);
  if (lane < 16) out[g * NC + lane] = logit - m - logf(s);
}

extern "C" void kernel_launch(void* const* d_in, const int* in_sizes, int n_in,
                              void* d_out, int out_size, void* d_ws, size_t ws_size,
                              hipStream_t stream) {
  const float* x = (const float*)d_in[0];
  const int* ei = (const int*)d_in[1];
  const int* batch = (const int*)d_in[2];
  const float* W1 = (const float*)d_in[3];
  const float* b1 = (const float*)d_in[4];
  const float* W2 = (const float*)d_in[5];
  const float* b2 = (const float*)d_in[6];
  const float* W3 = (const float*)d_in[7];
  const float* b3 = (const float*)d_in[8];
  const float* Wl = (const float*)d_in[9];
  const float* bl = (const float*)d_in[10];
  const int* src = ei;
  const int* dst = ei + NE;

  // workspace layout (~43 MB)
  int* bcnt = (int*)d_ws;                        // NBUK*NB1 = 76636 (scanned in place)
  int* bsum = bcnt + NBUK * NB1;                 // 1024
  int* bpref = bsum + 1024;                      // 1024
  int* gstart = bpref + 1024;                    // NG+2
  int* count = gstart + NG + 2;                  // NN
  int* offs = count + NN;                        // NN
  float* dinv = (float*)(offs + NN);             // NN
  float* gsum = (float*)(dinv + NN);             // NG*128
  unsigned int* packed = (unsigned int*)(gsum + NG * 128);  // NE
  int* csr = (int*)(packed + NE);                // NE (src only, 4B)
  unsigned int* t1f8 = (unsigned int*)(csr + NE);  // NN*4 (fp8x4, prescaled)
  unsigned int* h1f8 = t1f8 + (size_t)NN * 4;      // NN*4 (fp8x4, prescaled)
  unsigned int* t2p = h1f8 + (size_t)NN * 4;       // NN*8 (fp16x2)
  unsigned int* h2f8 = t2p + (size_t)NN * 8;       // NN*16 (fp8x4, prescaled)
  unsigned int* t3h = h2f8 + (size_t)NN * 16;      // NN*32 (fp16x2)
  unsigned int* w3s = t3h + (size_t)NN * 32;       // 4096 (B-fragment-swizzled W3)

  const int B = 256;
  const int NSC = NBUK * NB1;  // 76636

  // prep (gsum zero + W3 fragment pack) + CSR build (LDS atomics only)
  k_prep<<<260, 256, 0, stream>>>(W3, gsum, w3s);
  k_p1a<<<NB1, 256, 0, stream>>>(dst, bcnt);
  k_bounds<<<cdiv(NN + 1, B), B, 0, stream>>>(batch, gstart);
  k_scan1<<<cdiv(NSC, 256), 256, 0, stream>>>(bcnt, bcnt, bsum, NSC);
  k_scan2<<<1, 512, 0, stream>>>(bsum, bpref, cdiv(NSC, 256));
  k_scan3b<<<cdiv(NSC, B), B, 0, stream>>>(bcnt, bpref, NSC);
  k_p1b<<<NB1, 256, 0, stream>>>(src, dst, bcnt, packed);
  // p2 also emits t1f8 = fp8((x@W1)*di)  (fused dense1)
  k_p2<<<NBUK, 256, 0, stream>>>(packed, bcnt, x, W1, count, offs, dinv, csr, t1f8);

  // layer 1: h1f8 = fp8(relu(sum(t1f8)*di + b1)*di)
  k_agg16f8<true, true><<<cdiv(NN, 256), B, 0, stream>>>(
      t1f8, csr, offs, count, dinv, b1, h1f8);
  // layer 2: t2p = fp16(sum(h1f8)*di); h2f8 = fp8(relu(t2@W2+b2)*di)
  k_agg16f8<false, false><<<cdiv(NN, 256), B, 0, stream>>>(
      h1f8, csr, offs, count, dinv, nullptr, t2p);
  k_dense2_f8<<<cdiv((long long)NN * 16, B), B, 0, stream>>>(t2p, W2, b2, dinv, h2f8, NN);
  // layer 3: t3h = fp16(sum_fp8(h2f8)*di); MFMA dense3+relu+pool
  k_agg_b64f8<<<cdiv(NN, 64), B, 0, stream>>>(h2f8, csr, offs, count, dinv, t3h);
  k_d3pool_mfma<<<cdiv(cdiv(NN, 16), 4), 256, 0, stream>>>(t3h, w3s, b3, batch, gsum);

  // head
  k_head<<<NG / 4, B, 0, stream>>>(gsum, gstart, Wl, bl, (float*)d_out);
}

// Round 21
// 170.667 us; speedup vs baseline: 1.1185x; 1.1185x over previous
//
#include <hip/hip_runtime.h>
#include <hip/hip_fp16.h>

#define NN 100000
#define NE 1600000
#define NG 512
#define NC 16
#define NBUK 391  // coarse buckets = cdiv(NN,256), bucket = dst>>8
#define EPB 8192  // edges per phase-1 block
#define NB1 196   // cdiv(NE, EPB)

static inline int cdiv(long long a, int b) { return (int)((a + b - 1) / b); }

typedef __attribute__((ext_vector_type(2))) float floatx2;
typedef _Float16 half8_t __attribute__((ext_vector_type(8)));
typedef float f32x4_t __attribute__((ext_vector_type(4)));

__device__ __forceinline__ unsigned int pack_f16(float x, float y) {
  __half2 h = __floats2half2_rn(x, y);
  return *reinterpret_cast<unsigned int*>(&h);
}
__device__ __forceinline__ float2 unpack_f16(unsigned int u) {
  __half2 h = *reinterpret_cast<__half2*>(&u);
  return __half22float2(h);
}
// decode 4 fp8 (e4m3) from one uint into acc[0..3]
__device__ __forceinline__ void accf8(float* acc, unsigned int u) {
  floatx2 lo = __builtin_amdgcn_cvt_pk_f32_fp8(u, false);
  floatx2 hi = __builtin_amdgcn_cvt_pk_f32_fp8(u, true);
  acc[0] += lo.x; acc[1] += lo.y; acc[2] += hi.x; acc[3] += hi.y;
}
__device__ __forceinline__ unsigned int pack4_f8(float a, float b, float c, float d) {
  unsigned int u = 0;
  u = __builtin_amdgcn_cvt_pk_fp8_f32(a, b, u, false);
  u = __builtin_amdgcn_cvt_pk_fp8_f32(c, d, u, true);
  return u;
}
__device__ __forceinline__ half8_t as_h8(uint4 u) {
  half8_t h;
  __builtin_memcpy(&h, &u, 16);
  return h;
}

// prep: zero gsum (blocks 0..255) + build fp16 B-fragment-swizzled W3 (blocks 256..259)
__global__ void k_prep(const float* __restrict__ W3, float* __restrict__ gsum,
                       unsigned int* __restrict__ w3s) {
  int b = blockIdx.x, t = threadIdx.x;
  if (b < 256) {
    gsum[b * 256 + t] = 0.f;
    return;
  }
  int idx = (b - 256) * 256 + t;  // [0,1024)
  int c = idx >> 7, kb = (idx >> 6) & 1, l = idx & 63;
  int n = l & 15, kg = l >> 4;
#pragma unroll
  for (int j = 0; j < 4; ++j) {
    int k0 = kb * 32 + kg * 8 + 2 * j;
    w3s[idx * 4 + j] = pack_f16(W3[k0 * 128 + c * 16 + n], W3[(k0 + 1) * 128 + c * 16 + n]);
  }
}

// p1a: per-block coarse histogram (dst>>8) -> bcnt[bucket*NB1 + blk]  (LDS atomics only)
__global__ void k_p1a(const int* __restrict__ dst, int* __restrict__ bcnt) {
  __shared__ int sh[NBUK];
  int t = threadIdx.x, blk = blockIdx.x;
  for (int u = t; u < NBUK; u += 256) sh[u] = 0;
  __syncthreads();
  int e0 = blk * EPB;
#pragma unroll
  for (int k = 0; k < EPB / 256; ++k) {
    int e = e0 + k * 256 + t;
    if (e < NE) atomicAdd(&sh[dst[e] >> 8], 1);
  }
  __syncthreads();
  for (int u = t; u < NBUK; u += 256) bcnt[u * NB1 + blk] = sh[u];
}

// p1b: scatter edges into coarse-bucket partitions; packed = (dst&255)<<24 | src
__global__ void k_p1b(const int* __restrict__ src, const int* __restrict__ dst,
                      const int* __restrict__ bpos, unsigned int* __restrict__ packed) {
  __shared__ int sbase[NBUK];
  int t = threadIdx.x, blk = blockIdx.x;
  for (int u = t; u < NBUK; u += 256) sbase[u] = bpos[u * NB1 + blk];
  __syncthreads();
  int e0 = blk * EPB;
#pragma unroll
  for (int k = 0; k < EPB / 256; ++k) {
    int e = e0 + k * 256 + t;
    if (e < NE) {
      int d = dst[e];
      int pos = atomicAdd(&sbase[d >> 8], 1);  // LDS returning atomic
      packed[pos] = ((unsigned int)(d & 255) << 24) | (unsigned int)src[e];
    }
  }
}

// p2: per-bucket fine counting sort by dst-low8; emits count/offs/dinv + src-only csr
// + FUSED dense1: t1f8 = fp8((x@W1)*di)
__global__ void k_p2(const unsigned int* __restrict__ packed, const int* __restrict__ bpos,
                     const float* __restrict__ x, const float* __restrict__ W1,
                     int* __restrict__ count, int* __restrict__ offs,
                     float* __restrict__ dinv, int* __restrict__ csr,
                     unsigned int* __restrict__ t1f8) {
  __shared__ int sh[256], sc[256], cur[256];
  __shared__ float sW1[13 * 16];
  int t = threadIdx.x, u = blockIdx.x;
  if (t < 13 * 16) sW1[t] = W1[t];
  int s0 = bpos[u * NB1];
  int s1 = (u + 1 < NBUK) ? bpos[(u + 1) * NB1] : NE;
  sh[t] = 0;
  __syncthreads();
  for (int e = s0 + t; e < s1; e += 256) atomicAdd(&sh[packed[e] >> 24], 1);
  __syncthreads();
  sc[t] = sh[t];
  __syncthreads();
  for (int d = 1; d < 256; d <<= 1) {
    int a = (t >= d) ? sc[t - d] : 0;
    __syncthreads();
    sc[t] += a;
    __syncthreads();
  }
  int excl = sc[t] - sh[t];
  int node = u * 256 + t;
  if (node < NN) {
    count[node] = sh[t];
    offs[node] = s0 + excl;
    float di = rsqrtf((float)(sh[t] + 1));  // +1 self loop
    dinv[node] = di;
    // fused dense1: 16 outputs, fp8-packed
    float a[16];
#pragma unroll
    for (int o = 0; o < 16; ++o) a[o] = 0.f;
#pragma unroll
    for (int k = 0; k < 13; ++k) {
      float av = x[(size_t)node * 13 + k];
#pragma unroll
      for (int o = 0; o < 16; ++o) a[o] += av * sW1[k * 16 + o];
    }
    uint4 ov;
    ov.x = pack4_f8(a[0] * di, a[1] * di, a[2] * di, a[3] * di);
    ov.y = pack4_f8(a[4] * di, a[5] * di, a[6] * di, a[7] * di);
    ov.z = pack4_f8(a[8] * di, a[9] * di, a[10] * di, a[11] * di);
    ov.w = pack4_f8(a[12] * di, a[13] * di, a[14] * di, a[15] * di);
    ((uint4*)t1f8)[node] = ov;
  }
  cur[t] = s0 + excl;
  __syncthreads();
  for (int e = s0 + t; e < s1; e += 256) {
    unsigned int p = packed[e];
    int pos = atomicAdd(&cur[p >> 24], 1);  // LDS returning atomic
    csr[pos] = (int)(p & 0x00FFFFFFu);
  }
}

// graph boundaries from sorted batch
__global__ void k_bounds(const int* __restrict__ batch, int* __restrict__ gstart) {
  int i = blockIdx.x * blockDim.x + threadIdx.x;
  if (i > NN) return;
  int b = (i < NN) ? batch[i] : NG;
  int bp = (i > 0) ? batch[i - 1] : -1;
  for (int g = bp + 1; g <= b; ++g) gstart[g] = i;
}

// exclusive scan, 256/block; bsum gets block totals
__global__ void k_scan1(const int* __restrict__ in, int* __restrict__ out,
                        int* __restrict__ bsum, int n) {
  __shared__ int s[256];
  int t = threadIdx.x, i = blockIdx.x * 256 + t;
  int v = (i < n) ? in[i] : 0;
  s[t] = v;
  __syncthreads();
  for (int d = 1; d < 256; d <<= 1) {
    int a = (t >= d) ? s[t - d] : 0;
    __syncthreads();
    s[t] += a;
    __syncthreads();
  }
  if (i < n) out[i] = s[t] - v;  // exclusive
  if (t == 255) bsum[blockIdx.x] = s[255];
}

// single-block exclusive scan over <=512 values
__global__ void k_scan2(const int* __restrict__ in, int* __restrict__ out, int nb) {
  __shared__ int s[512];
  int t = threadIdx.x;
  int v = (t < nb) ? in[t] : 0;
  s[t] = v;
  __syncthreads();
  for (int d = 1; d < 512; d <<= 1) {
    int a = (t >= d) ? s[t - d] : 0;
    __syncthreads();
    s[t] += a;
    __syncthreads();
  }
  if (t < nb) out[t] = s[t] - v;
}

__global__ void k_scan3b(int* __restrict__ a, const int* __restrict__ bpref, int n) {
  int i = blockIdx.x * blockDim.x + threadIdx.x;
  if (i < n) a[i] += bpref[i >> 8];
}

// fp8 gather-reduce for F=16 rows (16B): 1 lane/node, uint4 per edge, unroll 4.
// BR: bias+relu epilogue (then prescale *di for next agg). OUTF8: fp8 out else fp16.
template <bool BR, bool OUTF8>
__global__ void k_agg16f8(const unsigned int* __restrict__ h, const int* __restrict__ csr,
                          const int* __restrict__ offs, const int* __restrict__ count,
                          const float* __restrict__ dinv, const float* __restrict__ bias,
                          unsigned int* __restrict__ out) {
  int wave = threadIdx.x >> 6, lane = threadIdx.x & 63;
  int i = (blockIdx.x * 4 + wave) * 64 + lane;
  if (i >= NN) return;
  int off = offs[i], cnt = count[i];
  float di = dinv[i];
  float acc[16];
#pragma unroll
  for (int t = 0; t < 16; ++t) acc[t] = 0.f;
  int j = 0;
#define DEC16(r)                                                            \
  {                                                                         \
    accf8(acc + 0, r.x);                                                    \
    accf8(acc + 4, r.y);                                                    \
    accf8(acc + 8, r.z);                                                    \
    accf8(acc + 12, r.w);                                                   \
  }
  for (; j + 3 < cnt; j += 4) {
    int s0 = csr[off + j], s1 = csr[off + j + 1];
    int s2 = csr[off + j + 2], s3 = csr[off + j + 3];
    uint4 r0 = ((const uint4*)h)[s0];
    uint4 r1 = ((const uint4*)h)[s1];
    uint4 r2 = ((const uint4*)h)[s2];
    uint4 r3 = ((const uint4*)h)[s3];
    DEC16(r0) DEC16(r1) DEC16(r2) DEC16(r3)
  }
  for (; j < cnt; ++j) {
    uint4 r0 = ((const uint4*)h)[csr[off + j]];
    DEC16(r0)
  }
  uint4 rs = ((const uint4*)h)[i];  // self loop (prescaled)
  DEC16(rs)
#undef DEC16
  float v[16];
#pragma unroll
  for (int t = 0; t < 16; ++t) {
    v[t] = acc[t] * di;
    if (BR) v[t] = fmaxf(v[t] + bias[t], 0.f) * di;  // relu+bias then prescale
  }
  if (OUTF8) {
    uint4 o;
    o.x = pack4_f8(v[0], v[1], v[2], v[3]);
    o.y = pack4_f8(v[4], v[5], v[6], v[7]);
    o.z = pack4_f8(v[8], v[9], v[10], v[11]);
    o.w = pack4_f8(v[12], v[13], v[14], v[15]);
    ((uint4*)out)[i] = o;
  } else {
    uint4 o0, o1;
    o0.x = pack_f16(v[0], v[1]);
    o0.y = pack_f16(v[2], v[3]);
    o0.z = pack_f16(v[4], v[5]);
    o0.w = pack_f16(v[6], v[7]);
    o1.x = pack_f16(v[8], v[9]);
    o1.y = pack_f16(v[10], v[11]);
    o1.z = pack_f16(v[12], v[13]);
    o1.w = pack_f16(v[14], v[15]);
    uint4* dst = (uint4*)(out + (size_t)i * 8);
    dst[0] = o0;
    dst[1] = o1;
  }
}

// fp8 gather-reduce F=64 (64B rows): 4 lanes/node, uint4 (16 fp8) per lane, unroll 4.
// Output t3h in fp16 (k-contiguous rows for the MFMA A-fragment).
__global__ void k_agg_b64f8(const unsigned int* __restrict__ h, const int* __restrict__ csr,
                            const int* __restrict__ offs, const int* __restrict__ count,
                            const float* __restrict__ dinv, unsigned int* __restrict__ out) {
  int wave = threadIdx.x >> 6, lane = threadIdx.x & 63;
  int i = (blockIdx.x * 4 + wave) * 16 + (lane >> 2);
  int q = lane & 3;  // uint4 index within 16-uint fp8 row
  if (i >= NN) return;
  int off = offs[i], cnt = count[i];
  float di = dinv[i];
  float acc[16];
#pragma unroll
  for (int t = 0; t < 16; ++t) acc[t] = 0.f;
  int j = 0;
#define DEC16(r)                                                            \
  {                                                                         \
    accf8(acc + 0, r.x);                                                    \
    accf8(acc + 4, r.y);                                                    \
    accf8(acc + 8, r.z);                                                    \
    accf8(acc + 12, r.w);                                                   \
  }
  for (; j + 3 < cnt; j += 4) {
    int s0 = csr[off + j], s1 = csr[off + j + 1];
    int s2 = csr[off + j + 2], s3 = csr[off + j + 3];
    uint4 r0 = ((const uint4*)(h + (size_t)s0 * 16))[q];
    uint4 r1 = ((const uint4*)(h + (size_t)s1 * 16))[q];
    uint4 r2 = ((const uint4*)(h + (size_t)s2 * 16))[q];
    uint4 r3 = ((const uint4*)(h + (size_t)s3 * 16))[q];
    DEC16(r0) DEC16(r1) DEC16(r2) DEC16(r3)
  }
  for (; j < cnt; ++j) {
    uint4 r0 = ((const uint4*)(h + (size_t)csr[off + j] * 16))[q];
    DEC16(r0)
  }
  uint4 rs = ((const uint4*)(h + (size_t)i * 16))[q];  // self loop (prescaled)
  DEC16(rs)
#undef DEC16
  uint4 o0, o1;
  o0.x = pack_f16(acc[0] * di, acc[1] * di);
  o0.y = pack_f16(acc[2] * di, acc[3] * di);
  o0.z = pack_f16(acc[4] * di, acc[5] * di);
  o0.w = pack_f16(acc[6] * di, acc[7] * di);
  o1.x = pack_f16(acc[8] * di, acc[9] * di);
  o1.y = pack_f16(acc[10] * di, acc[11] * di);
  o1.z = pack_f16(acc[12] * di, acc[13] * di);
  o1.w = pack_f16(acc[14] * di, acc[15] * di);
  uint4* dst = (uint4*)(out + (size_t)i * 32 + q * 8);
  dst[0] = o0;
  dst[1] = o1;
}

// dense2: h2f8 = fp8(relu(t2@W2+b2)*di); fp16-packed input rows; 4 outputs/thread
__global__ void k_dense2_f8(const unsigned int* __restrict__ a, const float* __restrict__ W,
                            const float* __restrict__ b, const float* __restrict__ dinv,
                            unsigned int* __restrict__ out, int n) {
  __shared__ float sW[16 * 64];
  __shared__ float sb[64];
  for (int t = threadIdx.x; t < 16 * 64; t += blockDim.x) sW[t] = W[t];
  for (int t = threadIdx.x; t < 64; t += blockDim.x) sb[t] = b[t];
  __syncthreads();
  int idx = blockIdx.x * blockDim.x + threadIdx.x;
  int i = idx >> 4, g4 = idx & 15;  // group of 4 output features
  if (i >= n) return;
  float av[16];
#pragma unroll
  for (int u = 0; u < 8; ++u) {
    float2 p = unpack_f16(a[(size_t)i * 8 + u]);
    av[2 * u] = p.x;
    av[2 * u + 1] = p.y;
  }
  float acc[4];
#pragma unroll
  for (int ko = 0; ko < 4; ++ko) acc[ko] = sb[4 * g4 + ko];
#pragma unroll
  for (int k = 0; k < 16; ++k) {
#pragma unroll
    for (int ko = 0; ko < 4; ++ko) acc[ko] += av[k] * sW[k * 64 + 4 * g4 + ko];
  }
  float di = dinv[i];
#pragma unroll
  for (int ko = 0; ko < 4; ++ko) acc[ko] = fmaxf(acc[ko], 0.f) * di;
  out[(size_t)i * 16 + g4] = pack4_f8(acc[0], acc[1], acc[2], acc[3]);
}

// MFMA dense3(64->128)+relu+segmented mean-pool.
__global__ __launch_bounds__(256) void k_d3pool_mfma(
    const unsigned int* __restrict__ t3h, const unsigned int* __restrict__ w3s,
    const float* __restrict__ b3, const int* __restrict__ batch,
    float* __restrict__ gsum) {
  int wu = blockIdx.x * 4 + (threadIdx.x >> 6);
  int lane = threadIdx.x & 63;
  int n0 = wu * 16;
  if (n0 >= NN) return;
  uint4 bf[8][2];
#pragma unroll
  for (int c = 0; c < 8; ++c)
#pragma unroll
    for (int kb = 0; kb < 2; ++kb)
      bf[c][kb] = ((const uint4*)w3s)[(c * 2 + kb) * 64 + lane];
  const uint4* arow = (const uint4*)(t3h + (size_t)(n0 + (lane & 15)) * 32);
  uint4 a0 = arow[lane >> 4];
  uint4 a1 = arow[4 + (lane >> 4)];
  f32x4_t acc[8];
#pragma unroll
  for (int c = 0; c < 8; ++c) {
    f32x4_t z = {0.f, 0.f, 0.f, 0.f};
    z = __builtin_amdgcn_mfma_f32_16x16x32_f16(as_h8(a0), as_h8(bf[c][0]), z, 0, 0, 0);
    z = __builtin_amdgcn_mfma_f32_16x16x32_f16(as_h8(a1), as_h8(bf[c][1]), z, 0, 0, 0);
    acc[c] = z;
  }
  float bias[8];
#pragma unroll
  for (int c = 0; c < 8; ++c) bias[c] = b3[c * 16 + (lane & 15)];
  int gf = batch[n0], gl = batch[n0 + 15];
  if (gf == gl) {
#pragma unroll
    for (int c = 0; c < 8; ++c) {
      float s = fmaxf(acc[c][0] + bias[c], 0.f) + fmaxf(acc[c][1] + bias[c], 0.f) +
                fmaxf(acc[c][2] + bias[c], 0.f) + fmaxf(acc[c][3] + bias[c], 0.f);
      s += __shfl_xor(s, 16);
      s += __shfl_xor(s, 32);
      if (lane < 16) atomicAdd(&gsum[gf * 128 + c * 16 + lane], s);
    }
  } else {
#pragma unroll
    for (int r = 0; r < 4; ++r) {
      int g = batch[n0 + (lane >> 4) * 4 + r];
#pragma unroll
      for (int c = 0; c < 8; ++c)
        atomicAdd(&gsum[g * 128 + c * 16 + (lane & 15)],
                  fmaxf(acc[c][r] + bias[c], 0.f));
    }
  }
}

// one wave per graph: logits = (gsum/cnt) @ Wl + bl; log_softmax over 16 classes
__global__ void k_head(const float* __restrict__ gsum, const int* __restrict__ gstart,
                       const float* __restrict__ Wl, const float* __restrict__ bl,
                       float* __restrict__ out) {
  int wave = threadIdx.x >> 6, lane = threadIdx.x & 63;
  int g = blockIdx.x * 4 + wave;
  if (g >= NG) return;
  int c = lane & 15, part = lane >> 4;
  float acc = 0.f;
#pragma unroll
  for (int kk = 0; kk < 32; ++kk) {
    int k = part * 32 + kk;
    acc += gsum[g * 128 + k] * Wl[k * NC + c];
  }
  acc += __shfl_xor(acc, 16);
  acc += __shfl_xor(acc, 32);
  int cnt = gstart[g + 1] - gstart[g];
  float inv = 1.0f / (float)max(cnt, 1);
  float logit = acc * inv + bl[c];
  float m = logit;
#pragma unroll
  for (int d = 1; d < 16; d <<= 1) m = fmaxf(m, __shfl_xor(m, d));
  float ex = expf(logit - m), s = ex;
#pragma unroll
  for (int d = 1; d < 16; d <<= 1) s += __shfl_xor(s, d);
  if (lane < 16) out[g * NC + lane] = logit - m - logf(s);
}

extern "C" void kernel_launch(void* const* d_in, const int* in_sizes, int n_in,
                              void* d_out, int out_size, void* d_ws, size_t ws_size,
                              hipStream_t stream) {
  const float* x = (const float*)d_in[0];
  const int* ei = (const int*)d_in[1];
  const int* batch = (const int*)d_in[2];
  const float* W1 = (const float*)d_in[3];
  const float* b1 = (const float*)d_in[4];
  const float* W2 = (const float*)d_in[5];
  const float* b2 = (const float*)d_in[6];
  const float* W3 = (const float*)d_in[7];
  const float* b3 = (const float*)d_in[8];
  const float* Wl = (const float*)d_in[9];
  const float* bl = (const float*)d_in[10];
  const int* src = ei;
  const int* dst = ei + NE;

  // workspace layout (~43 MB)
  int* bcnt = (int*)d_ws;                        // NBUK*NB1 = 76636 (scanned in place)
  int* bsum = bcnt + NBUK * NB1;                 // 1024
  int* bpref = bsum + 1024;                      // 1024
  int* gstart = bpref + 1024;                    // NG+2
  int* count = gstart + NG + 2;                  // NN
  int* offs = count + NN;                        // NN
  float* dinv = (float*)(offs + NN);             // NN
  float* gsum = (float*)(dinv + NN);             // NG*128
  unsigned int* packed = (unsigned int*)(gsum + NG * 128);  // NE
  int* csr = (int*)(packed + NE);                // NE (src only, 4B)
  unsigned int* t1f8 = (unsigned int*)(csr + NE);  // NN*4 (fp8x4, prescaled)
  unsigned int* h1f8 = t1f8 + (size_t)NN * 4;      // NN*4 (fp8x4, prescaled)
  unsigned int* t2p = h1f8 + (size_t)NN * 4;       // NN*8 (fp16x2)
  unsigned int* h2f8 = t2p + (size_t)NN * 8;       // NN*16 (fp8x4, prescaled)
  unsigned int* t3h = h2f8 + (size_t)NN * 16;      // NN*32 (fp16x2)
  unsigned int* w3s = t3h + (size_t)NN * 32;       // 4096 (B-fragment-swizzled W3)

  const int B = 256;
  const int NSC = NBUK * NB1;  // 76636

  // prep (gsum zero + W3 fragment pack) + CSR build (LDS atomics only)
  k_prep<<<260, 256, 0, stream>>>(W3, gsum, w3s);
  k_p1a<<<NB1, 256, 0, stream>>>(dst, bcnt);
  k_bounds<<<cdiv(NN + 1, B), B, 0, stream>>>(batch, gstart);
  k_scan1<<<cdiv(NSC, 256), 256, 0, stream>>>(bcnt, bcnt, bsum, NSC);
  k_scan2<<<1, 512, 0, stream>>>(bsum, bpref, cdiv(NSC, 256));
  k_scan3b<<<cdiv(NSC, B), B, 0, stream>>>(bcnt, bpref, NSC);
  k_p1b<<<NB1, 256, 0, stream>>>(src, dst, bcnt, packed);
  // p2 also emits t1f8 = fp8((x@W1)*di)  (fused dense1)
  k_p2<<<NBUK, 256, 0, stream>>>(packed, bcnt, x, W1, count, offs, dinv, csr, t1f8);

  // layer 1: h1f8 = fp8(relu(sum(t1f8)*di + b1)*di)
  k_agg16f8<true, true><<<cdiv(NN, 256), B, 0, stream>>>(
      t1f8, csr, offs, count, dinv, b1, h1f8);
  // layer 2: t2p = fp16(sum(h1f8)*di); h2f8 = fp8(relu(t2@W2+b2)*di)
  k_agg16f8<false, false><<<cdiv(NN, 256), B, 0, stream>>>(
      h1f8, csr, offs, count, dinv, nullptr, t2p);
  k_dense2_f8<<<cdiv((long long)NN * 16, B), B, 0, stream>>>(t2p, W2, b2, dinv, h2f8, NN);
  // layer 3: t3h = fp16(sum_fp8(h2f8)*di); MFMA dense3+relu+pool
  k_agg_b64f8<<<cdiv(NN, 64), B, 0, stream>>>(h2f8, csr, offs, count, dinv, t3h);
  k_d3pool_mfma<<<cdiv(cdiv(NN, 16), 4), 256, 0, stream>>>(t3h, w3s, b3, batch, gsum);

  // head
  k_head<<<NG / 4, B, 0, stream>>>(gsum, gstart, Wl, bl, (float*)d_out);
}

// Round 22
// 162.827 us; speedup vs baseline: 1.1724x; 1.0481x over previous
//
#include <hip/hip_runtime.h>
#include <hip/hip_fp16.h>

#define NN 100000
#define NE 1600000
#define NG 512
#define NC 16
#define NBUK 391  // coarse buckets = cdiv(NN,256), bucket = dst>>8
#define EPB 8192  // edges per phase-1 block
#define NB1 196   // cdiv(NE, EPB)

static inline int cdiv(long long a, int b) { return (int)((a + b - 1) / b); }

typedef __attribute__((ext_vector_type(2))) float floatx2;
typedef _Float16 half8_t __attribute__((ext_vector_type(8)));
typedef float f32x4_t __attribute__((ext_vector_type(4)));

__device__ __forceinline__ unsigned int pack_f16(float x, float y) {
  __half2 h = __floats2half2_rn(x, y);
  return *reinterpret_cast<unsigned int*>(&h);
}
__device__ __forceinline__ float2 unpack_f16(unsigned int u) {
  __half2 h = *reinterpret_cast<__half2*>(&u);
  return __half22float2(h);
}
// decode 4 fp8 (e4m3) from one uint into acc[0..3]
__device__ __forceinline__ void accf8(float* acc, unsigned int u) {
  floatx2 lo = __builtin_amdgcn_cvt_pk_f32_fp8(u, false);
  floatx2 hi = __builtin_amdgcn_cvt_pk_f32_fp8(u, true);
  acc[0] += lo.x; acc[1] += lo.y; acc[2] += hi.x; acc[3] += hi.y;
}
__device__ __forceinline__ unsigned int pack4_f8(float a, float b, float c, float d) {
  unsigned int u = 0;
  u = __builtin_amdgcn_cvt_pk_fp8_f32(a, b, u, false);
  u = __builtin_amdgcn_cvt_pk_fp8_f32(c, d, u, true);
  return u;
}
__device__ __forceinline__ half8_t as_h8(uint4 u) {
  half8_t h;
  __builtin_memcpy(&h, &u, 16);
  return h;
}

// k_init: fuses gsum-zero (blocks 0..255), w3s pack (256..259),
// graph bounds (260..651), and p1a coarse histogram (652..847).
__global__ void k_init(const float* __restrict__ W3, float* __restrict__ gsum,
                       unsigned int* __restrict__ w3s, const int* __restrict__ batch,
                       int* __restrict__ gstart, const int* __restrict__ dst,
                       int* __restrict__ bcnt) {
  __shared__ int sh[NBUK];
  int b = blockIdx.x, t = threadIdx.x;
  if (b < 256) {
    gsum[b * 256 + t] = 0.f;
    return;
  }
  if (b < 260) {
    int idx = (b - 256) * 256 + t;  // [0,1024)
    int c = idx >> 7, kb = (idx >> 6) & 1, l = idx & 63;
    int n = l & 15, kg = l >> 4;
#pragma unroll
    for (int j = 0; j < 4; ++j) {
      int k0 = kb * 32 + kg * 8 + 2 * j;
      w3s[idx * 4 + j] =
          pack_f16(W3[k0 * 128 + c * 16 + n], W3[(k0 + 1) * 128 + c * 16 + n]);
    }
    return;
  }
  if (b < 652) {
    int i = (b - 260) * 256 + t;
    if (i > NN) return;
    int bb = (i < NN) ? batch[i] : NG;
    int bp = (i > 0) ? batch[i - 1] : -1;
    for (int g = bp + 1; g <= bb; ++g) gstart[g] = i;
    return;
  }
  // p1a: coarse histogram
  int blk = b - 652;
  for (int u = t; u < NBUK; u += 256) sh[u] = 0;
  __syncthreads();
  int e0 = blk * EPB;
#pragma unroll
  for (int k = 0; k < EPB / 256; ++k) {
    int e = e0 + k * 256 + t;
    if (e < NE) atomicAdd(&sh[dst[e] >> 8], 1);
  }
  __syncthreads();
  for (int u = t; u < NBUK; u += 256) bcnt[u * NB1 + blk] = sh[u];
}

// p1b: scatter edges into coarse-bucket partitions; packed = (dst&255)<<24 | src
// base = bcnt(exclusive within chunk) + bpref(chunk prefix)  [scan3b folded in]
__global__ void k_p1b(const int* __restrict__ src, const int* __restrict__ dst,
                      const int* __restrict__ bpos, const int* __restrict__ bpref,
                      unsigned int* __restrict__ packed) {
  __shared__ int sbase[NBUK];
  int t = threadIdx.x, blk = blockIdx.x;
  for (int u = t; u < NBUK; u += 256) {
    int idx = u * NB1 + blk;
    sbase[u] = bpos[idx] + bpref[idx >> 8];
  }
  __syncthreads();
  int e0 = blk * EPB;
#pragma unroll
  for (int k = 0; k < EPB / 256; ++k) {
    int e = e0 + k * 256 + t;
    if (e < NE) {
      int d = dst[e];
      int pos = atomicAdd(&sbase[d >> 8], 1);  // LDS returning atomic
      packed[pos] = ((unsigned int)(d & 255) << 24) | (unsigned int)src[e];
    }
  }
}

// p2: per-bucket fine counting sort by dst-low8; emits count/offs/dinv + src-only csr
// + FUSED dense1: t1f8 = fp8((x@W1)*di).  bpref folded in (scan3b eliminated).
__global__ void k_p2(const unsigned int* __restrict__ packed, const int* __restrict__ bpos,
                     const int* __restrict__ bpref, const float* __restrict__ x,
                     const float* __restrict__ W1, int* __restrict__ count,
                     int* __restrict__ offs, float* __restrict__ dinv,
                     int* __restrict__ csr, unsigned int* __restrict__ t1f8) {
  __shared__ int sh[256], sc[256], cur[256];
  __shared__ float sW1[13 * 16];
  int t = threadIdx.x, u = blockIdx.x;
  if (t < 13 * 16) sW1[t] = W1[t];
  int i0 = u * NB1;
  int s0 = bpos[i0] + bpref[i0 >> 8];
  int s1 = (u + 1 < NBUK) ? (bpos[i0 + NB1] + bpref[(i0 + NB1) >> 8]) : NE;
  sh[t] = 0;
  __syncthreads();
  for (int e = s0 + t; e < s1; e += 256) atomicAdd(&sh[packed[e] >> 24], 1);
  __syncthreads();
  sc[t] = sh[t];
  __syncthreads();
  for (int d = 1; d < 256; d <<= 1) {
    int a = (t >= d) ? sc[t - d] : 0;
    __syncthreads();
    sc[t] += a;
    __syncthreads();
  }
  int excl = sc[t] - sh[t];
  int node = u * 256 + t;
  if (node < NN) {
    count[node] = sh[t];
    offs[node] = s0 + excl;
    float di = rsqrtf((float)(sh[t] + 1));  // +1 self loop
    dinv[node] = di;
    // fused dense1: 16 outputs, fp8-packed
    float a[16];
#pragma unroll
    for (int o = 0; o < 16; ++o) a[o] = 0.f;
#pragma unroll
    for (int k = 0; k < 13; ++k) {
      float av = x[(size_t)node * 13 + k];
#pragma unroll
      for (int o = 0; o < 16; ++o) a[o] += av * sW1[k * 16 + o];
    }
    uint4 ov;
    ov.x = pack4_f8(a[0] * di, a[1] * di, a[2] * di, a[3] * di);
    ov.y = pack4_f8(a[4] * di, a[5] * di, a[6] * di, a[7] * di);
    ov.z = pack4_f8(a[8] * di, a[9] * di, a[10] * di, a[11] * di);
    ov.w = pack4_f8(a[12] * di, a[13] * di, a[14] * di, a[15] * di);
    ((uint4*)t1f8)[node] = ov;
  }
  cur[t] = s0 + excl;
  __syncthreads();
  for (int e = s0 + t; e < s1; e += 256) {
    unsigned int p = packed[e];
    int pos = atomicAdd(&cur[p >> 24], 1);  // LDS returning atomic
    csr[pos] = (int)(p & 0x00FFFFFFu);
  }
}

// exclusive scan, 256/block; bsum gets block totals
__global__ void k_scan1(const int* __restrict__ in, int* __restrict__ out,
                        int* __restrict__ bsum, int n) {
  __shared__ int s[256];
  int t = threadIdx.x, i = blockIdx.x * 256 + t;
  int v = (i < n) ? in[i] : 0;
  s[t] = v;
  __syncthreads();
  for (int d = 1; d < 256; d <<= 1) {
    int a = (t >= d) ? s[t - d] : 0;
    __syncthreads();
    s[t] += a;
    __syncthreads();
  }
  if (i < n) out[i] = s[t] - v;  // exclusive
  if (t == 255) bsum[blockIdx.x] = s[255];
}

// single-block exclusive scan over <=512 values
__global__ void k_scan2(const int* __restrict__ in, int* __restrict__ out, int nb) {
  __shared__ int s[512];
  int t = threadIdx.x;
  int v = (t < nb) ? in[t] : 0;
  s[t] = v;
  __syncthreads();
  for (int d = 1; d < 512; d <<= 1) {
    int a = (t >= d) ? s[t - d] : 0;
    __syncthreads();
    s[t] += a;
    __syncthreads();
  }
  if (t < nb) out[t] = s[t] - v;
}

// fp8 gather-reduce for F=16 rows (16B): 1 lane/node, uint4 per edge, unroll 4.
// BR: bias+relu epilogue (then prescale *di for next agg). OUTF8: fp8 out else fp16.
template <bool BR, bool OUTF8>
__global__ void k_agg16f8(const unsigned int* __restrict__ h, const int* __restrict__ csr,
                          const int* __restrict__ offs, const int* __restrict__ count,
                          const float* __restrict__ dinv, const float* __restrict__ bias,
                          unsigned int* __restrict__ out) {
  int wave = threadIdx.x >> 6, lane = threadIdx.x & 63;
  int i = (blockIdx.x * 4 + wave) * 64 + lane;
  if (i >= NN) return;
  int off = offs[i], cnt = count[i];
  float di = dinv[i];
  float acc[16];
#pragma unroll
  for (int t = 0; t < 16; ++t) acc[t] = 0.f;
  int j = 0;
#define DEC16(r)                                                            \
  {                                                                         \
    accf8(acc + 0, r.x);                                                    \
    accf8(acc + 4, r.y);                                                    \
    accf8(acc + 8, r.z);                                                    \
    accf8(acc + 12, r.w);                                                   \
  }
  for (; j + 3 < cnt; j += 4) {
    int s0 = csr[off + j], s1 = csr[off + j + 1];
    int s2 = csr[off + j + 2], s3 = csr[off + j + 3];
    uint4 r0 = ((const uint4*)h)[s0];
    uint4 r1 = ((const uint4*)h)[s1];
    uint4 r2 = ((const uint4*)h)[s2];
    uint4 r3 = ((const uint4*)h)[s3];
    DEC16(r0) DEC16(r1) DEC16(r2) DEC16(r3)
  }
  for (; j < cnt; ++j) {
    uint4 r0 = ((const uint4*)h)[csr[off + j]];
    DEC16(r0)
  }
  uint4 rs = ((const uint4*)h)[i];  // self loop (prescaled)
  DEC16(rs)
#undef DEC16
  float v[16];
#pragma unroll
  for (int t = 0; t < 16; ++t) {
    v[t] = acc[t] * di;
    if (BR) v[t] = fmaxf(v[t] + bias[t], 0.f) * di;  // relu+bias then prescale
  }
  if (OUTF8) {
    uint4 o;
    o.x = pack4_f8(v[0], v[1], v[2], v[3]);
    o.y = pack4_f8(v[4], v[5], v[6], v[7]);
    o.z = pack4_f8(v[8], v[9], v[10], v[11]);
    o.w = pack4_f8(v[12], v[13], v[14], v[15]);
    ((uint4*)out)[i] = o;
  } else {
    uint4 o0, o1;
    o0.x = pack_f16(v[0], v[1]);
    o0.y = pack_f16(v[2], v[3]);
    o0.z = pack_f16(v[4], v[5]);
    o0.w = pack_f16(v[6], v[7]);
    o1.x = pack_f16(v[8], v[9]);
    o1.y = pack_f16(v[10], v[11]);
    o1.z = pack_f16(v[12], v[13]);
    o1.w = pack_f16(v[14], v[15]);
    uint4* dst = (uint4*)(out + (size_t)i * 8);
    dst[0] = o0;
    dst[1] = o1;
  }
}

// fp8 gather-reduce F=64 (64B rows): 4 lanes/node, uint4 (16 fp8) per lane, unroll 4.
// Output t3h in fp16 (k-contiguous rows for the MFMA A-fragment).
__global__ void k_agg_b64f8(const unsigned int* __restrict__ h, const int* __restrict__ csr,
                            const int* __restrict__ offs, const int* __restrict__ count,
                            const float* __restrict__ dinv, unsigned int* __restrict__ out) {
  int wave = threadIdx.x >> 6, lane = threadIdx.x & 63;
  int i = (blockIdx.x * 4 + wave) * 16 + (lane >> 2);
  int q = lane & 3;  // uint4 index within 16-uint fp8 row
  if (i >= NN) return;
  int off = offs[i], cnt = count[i];
  float di = dinv[i];
  float acc[16];
#pragma unroll
  for (int t = 0; t < 16; ++t) acc[t] = 0.f;
  int j = 0;
#define DEC16(r)                                                            \
  {                                                                         \
    accf8(acc + 0, r.x);                                                    \
    accf8(acc + 4, r.y);                                                    \
    accf8(acc + 8, r.z);                                                    \
    accf8(acc + 12, r.w);                                                   \
  }
  for (; j + 3 < cnt; j += 4) {
    int s0 = csr[off + j], s1 = csr[off + j + 1];
    int s2 = csr[off + j + 2], s3 = csr[off + j + 3];
    uint4 r0 = ((const uint4*)(h + (size_t)s0 * 16))[q];
    uint4 r1 = ((const uint4*)(h + (size_t)s1 * 16))[q];
    uint4 r2 = ((const uint4*)(h + (size_t)s2 * 16))[q];
    uint4 r3 = ((const uint4*)(h + (size_t)s3 * 16))[q];
    DEC16(r0) DEC16(r1) DEC16(r2) DEC16(r3)
  }
  for (; j < cnt; ++j) {
    uint4 r0 = ((const uint4*)(h + (size_t)csr[off + j] * 16))[q];
    DEC16(r0)
  }
  uint4 rs = ((const uint4*)(h + (size_t)i * 16))[q];  // self loop (prescaled)
  DEC16(rs)
#undef DEC16
  uint4 o0, o1;
  o0.x = pack_f16(acc[0] * di, acc[1] * di);
  o0.y = pack_f16(acc[2] * di, acc[3] * di);
  o0.z = pack_f16(acc[4] * di, acc[5] * di);
  o0.w = pack_f16(acc[6] * di, acc[7] * di);
  o1.x = pack_f16(acc[8] * di, acc[9] * di);
  o1.y = pack_f16(acc[10] * di, acc[11] * di);
  o1.z = pack_f16(acc[12] * di, acc[13] * di);
  o1.w = pack_f16(acc[14] * di, acc[15] * di);
  uint4* dst = (uint4*)(out + (size_t)i * 32 + q * 8);
  dst[0] = o0;
  dst[1] = o1;
}

// dense2: h2f8 = fp8(relu(t2@W2+b2)*di); fp16-packed input rows; 4 outputs/thread
__global__ void k_dense2_f8(const unsigned int* __restrict__ a, const float* __restrict__ W,
                            const float* __restrict__ b, const float* __restrict__ dinv,
                            unsigned int* __restrict__ out, int n) {
  __shared__ float sW[16 * 64];
  __shared__ float sb[64];
  for (int t = threadIdx.x; t < 16 * 64; t += blockDim.x) sW[t] = W[t];
  for (int t = threadIdx.x; t < 64; t += blockDim.x) sb[t] = b[t];
  __syncthreads();
  int idx = blockIdx.x * blockDim.x + threadIdx.x;
  int i = idx >> 4, g4 = idx & 15;  // group of 4 output features
  if (i >= n) return;
  float av[16];
#pragma unroll
  for (int u = 0; u < 8; ++u) {
    float2 p = unpack_f16(a[(size_t)i * 8 + u]);
    av[2 * u] = p.x;
    av[2 * u + 1] = p.y;
  }
  float acc[4];
#pragma unroll
  for (int ko = 0; ko < 4; ++ko) acc[ko] = sb[4 * g4 + ko];
#pragma unroll
  for (int k = 0; k < 16; ++k) {
#pragma unroll
    for (int ko = 0; ko < 4; ++ko) acc[ko] += av[k] * sW[k * 64 + 4 * g4 + ko];
  }
  float di = dinv[i];
#pragma unroll
  for (int ko = 0; ko < 4; ++ko) acc[ko] = fmaxf(acc[ko], 0.f) * di;
  out[(size_t)i * 16 + g4] = pack4_f8(acc[0], acc[1], acc[2], acc[3]);
}

// MFMA dense3(64->128)+relu+segmented mean-pool.
__global__ __launch_bounds__(256) void k_d3pool_mfma(
    const unsigned int* __restrict__ t3h, const unsigned int* __restrict__ w3s,
    const float* __restrict__ b3, const int* __restrict__ batch,
    float* __restrict__ gsum) {
  int wu = blockIdx.x * 4 + (threadIdx.x >> 6);
  int lane = threadIdx.x & 63;
  int n0 = wu * 16;
  if (n0 >= NN) return;
  uint4 bf[8][2];
#pragma unroll
  for (int c = 0; c < 8; ++c)
#pragma unroll
    for (int kb = 0; kb < 2; ++kb)
      bf[c][kb] = ((const uint4*)w3s)[(c * 2 + kb) * 64 + lane];
  const uint4* arow = (const uint4*)(t3h + (size_t)(n0 + (lane & 15)) * 32);
  uint4 a0 = arow[lane >> 4];
  uint4 a1 = arow[4 + (lane >> 4)];
  f32x4_t acc[8];
#pragma unroll
  for (int c = 0; c < 8; ++c) {
    f32x4_t z = {0.f, 0.f, 0.f, 0.f};
    z = __builtin_amdgcn_mfma_f32_16x16x32_f16(as_h8(a0), as_h8(bf[c][0]), z, 0, 0, 0);
    z = __builtin_amdgcn_mfma_f32_16x16x32_f16(as_h8(a1), as_h8(bf[c][1]), z, 0, 0, 0);
    acc[c] = z;
  }
  float bias[8];
#pragma unroll
  for (int c = 0; c < 8; ++c) bias[c] = b3[c * 16 + (lane & 15)];
  int gf = batch[n0], gl = batch[n0 + 15];
  if (gf == gl) {
#pragma unroll
    for (int c = 0; c < 8; ++c) {
      float s = fmaxf(acc[c][0] + bias[c], 0.f) + fmaxf(acc[c][1] + bias[c], 0.f) +
                fmaxf(acc[c][2] + bias[c], 0.f) + fmaxf(acc[c][3] + bias[c], 0.f);
      s += __shfl_xor(s, 16);
      s += __shfl_xor(s, 32);
      if (lane < 16) atomicAdd(&gsum[gf * 128 + c * 16 + lane], s);
    }
  } else {
#pragma unroll
    for (int r = 0; r < 4; ++r) {
      int g = batch[n0 + (lane >> 4) * 4 + r];
#pragma unroll
      for (int c = 0; c < 8; ++c)
        atomicAdd(&gsum[g * 128 + c * 16 + (lane & 15)],
                  fmaxf(acc[c][r] + bias[c], 0.f));
    }
  }
}

// one wave per graph: logits = (gsum/cnt) @ Wl + bl; log_softmax over 16 classes
__global__ void k_head(const float* __restrict__ gsum, const int* __restrict__ gstart,
                       const float* __restrict__ Wl, const float* __restrict__ bl,
                       float* __restrict__ out) {
  int wave = threadIdx.x >> 6, lane = threadIdx.x & 63;
  int g = blockIdx.x * 4 + wave;
  if (g >= NG) return;
  int c = lane & 15, part = lane >> 4;
  float acc = 0.f;
#pragma unroll
  for (int kk = 0; kk < 32; ++kk) {
    int k = part * 32 + kk;
    acc += gsum[g * 128 + k] * Wl[k * NC + c];
  }
  acc += __shfl_xor(acc, 16);
  acc += __shfl_xor(acc, 32);
  int cnt = gstart[g + 1] - gstart[g];
  float inv = 1.0f / (float)max(cnt, 1);
  float logit = acc * inv + bl[c];
  float m = logit;
#pragma unroll
  for (int d = 1; d < 16; d <<= 1) m = fmaxf(m, __shfl_xor(m, d));
  float ex = expf(logit - m), s = ex;
#pragma unroll
  for (int d = 1; d < 16; d <<= 1) s += __shfl_xor(s, d);
  if (lane < 16) out[g * NC + lane] = logit - m - logf(s);
}

extern "C" void kernel_launch(void* const* d_in, const int* in_sizes, int n_in,
                              void* d_out, int out_size, void* d_ws, size_t ws_size,
                              hipStream_t stream) {
  const float* x = (const float*)d_in[0];
  const int* ei = (const int*)d_in[1];
  const int* batch = (const int*)d_in[2];
  const float* W1 = (const float*)d_in[3];
  const float* b1 = (const float*)d_in[4];
  const float* W2 = (const float*)d_in[5];
  const float* b2 = (const float*)d_in[6];
  const float* W3 = (const float*)d_in[7];
  const float* b3 = (const float*)d_in[8];
  const float* Wl = (const float*)d_in[9];
  const float* bl = (const float*)d_in[10];
  const int* src = ei;
  const int* dst = ei + NE;

  // workspace layout (~43 MB)
  int* bcnt = (int*)d_ws;                        // NBUK*NB1 = 76636 (scanned in place)
  int* bsum = bcnt + NBUK * NB1;                 // 1024
  int* bpref = bsum + 1024;                      // 1024
  int* gstart = bpref + 1024;                    // NG+2
  int* count = gstart + NG + 2;                  // NN
  int* offs = count + NN;                        // NN
  float* dinv = (float*)(offs + NN);             // NN
  float* gsum = (float*)(dinv + NN);             // NG*128
  unsigned int* packed = (unsigned int*)(gsum + NG * 128);  // NE
  int* csr = (int*)(packed + NE);                // NE (src only, 4B)
  unsigned int* t1f8 = (unsigned int*)(csr + NE);  // NN*4 (fp8x4, prescaled)
  unsigned int* h1f8 = t1f8 + (size_t)NN * 4;      // NN*4 (fp8x4, prescaled)
  unsigned int* t2p = h1f8 + (size_t)NN * 4;       // NN*8 (fp16x2)
  unsigned int* h2f8 = t2p + (size_t)NN * 8;       // NN*16 (fp8x4, prescaled)
  unsigned int* t3h = h2f8 + (size_t)NN * 16;      // NN*32 (fp16x2)
  unsigned int* w3s = t3h + (size_t)NN * 32;       // 4096 (B-fragment-swizzled W3)

  const int B = 256;
  const int NSC = NBUK * NB1;  // 76636

  // fused init (gsum zero + w3s + bounds + p1a) + CSR build (LDS atomics only)
  k_init<<<848, 256, 0, stream>>>(W3, gsum, w3s, batch, gstart, dst, bcnt);
  k_scan1<<<cdiv(NSC, 256), 256, 0, stream>>>(bcnt, bcnt, bsum, NSC);
  k_scan2<<<1, 512, 0, stream>>>(bsum, bpref, cdiv(NSC, 256));
  k_p1b<<<NB1, 256, 0, stream>>>(src, dst, bcnt, bpref, packed);
  // p2 also emits t1f8 = fp8((x@W1)*di)  (fused dense1)
  k_p2<<<NBUK, 256, 0, stream>>>(packed, bcnt, bpref, x, W1, count, offs, dinv, csr, t1f8);

  // layer 1: h1f8 = fp8(relu(sum(t1f8)*di + b1)*di)
  k_agg16f8<true, true><<<cdiv(NN, 256), B, 0, stream>>>(
      t1f8, csr, offs, count, dinv, b1, h1f8);
  // layer 2: t2p = fp16(sum(h1f8)*di); h2f8 = fp8(relu(t2@W2+b2)*di)
  k_agg16f8<false, false><<<cdiv(NN, 256), B, 0, stream>>>(
      h1f8, csr, offs, count, dinv, nullptr, t2p);
  k_dense2_f8<<<cdiv((long long)NN * 16, B), B, 0, stream>>>(t2p, W2, b2, dinv, h2f8, NN);
  // layer 3: t3h = fp16(sum_fp8(h2f8)*di); MFMA dense3+relu+pool
  k_agg_b64f8<<<cdiv(NN, 64), B, 0, stream>>>(h2f8, csr, offs, count, dinv, t3h);
  k_d3pool_mfma<<<cdiv(cdiv(NN, 16), 4), 256, 0, stream>>>(t3h, w3s, b3, batch, gsum);

  // head
  k_head<<<NG / 4, B, 0, stream>>>(gsum, gstart, Wl, bl, (float*)d_out);
}